// Round 1
// baseline (542.990 us; speedup 1.0000x reference)
//
#include <hip/hip_runtime.h>
#include <math.h>

// OmniRobotPhysics: B independent trajectories, T sequential dynamics steps.
// One thread per trajectory; 64-thread blocks spread the 128 waves across CUs.
//
// Algebraic simplifications vs reference (all ~1-ulp-per-step reorderings):
//  - (cmd - bv) @ F.T @ F folded to (cmd - bv) @ (F F^T); F F^T has
//    M01 = M02 = 0 analytically, so x decouples and (y,w) is a 2x2.
//  - atan2(sin(t),cos(t)) wrap -> conditional +/-2pi (exact for |t| < 3pi).
//  - divides by mass/inertia -> multiplies by precomputed reciprocals.

#define MASS_F 2.8f
#define DT_F 0.016f

// F F^T entries, computed in double from angles {60,130,230,300} deg, R=0.09:
#define M00_F 2.6736481776669306f
#define M11_F 1.3263518223330697f
#define M12_F (-0.025701769743577074f)
#define M22_F 0.0324f

#define PI_F 3.14159265358979323846f
#define TWO_PI_F 6.28318530717958647692f

__device__ __forceinline__ float softplus_f(float x) {
    // log(1+exp(x)), stable: max(x,0) + log1p(exp(-|x|))
    float ax = fabsf(x);
    return fmaxf(x, 0.0f) + log1pf(expf(-ax));
}

__device__ __forceinline__ float sgn_f(float v) {
    // matches jnp.sign (0 at 0)
    return (v > 0.0f ? 1.0f : 0.0f) - (v < 0.0f ? 1.0f : 0.0f);
}

__global__ __launch_bounds__(64, 1)
void omni_robot_kernel(const float* __restrict__ init_state,   // (B, 6)
                       const float* __restrict__ cmd_all,      // (B, T, 3)
                       const float* __restrict__ com_offset,   // (2,)
                       const float* __restrict__ inertia_p,    // (1,)
                       const float* __restrict__ gain_p,       // (1,)
                       const float* __restrict__ grip_p,       // (1,)
                       const float* __restrict__ drag_v_p,     // (3,)
                       const float* __restrict__ drag_c_p,     // (3,)
                       float* __restrict__ out,                // (B, T+1, 6)
                       int B, int T)
{
    const int b = blockIdx.x * blockDim.x + threadIdx.x;
    if (b >= B) return;

    // --- per-launch scalars (uniform; cheap, computed once per thread) ---
    const float inertia = softplus_f(inertia_p[0]) + 1e-4f;
    const float gain    = softplus_f(gain_p[0]);
    const float grip    = softplus_f(grip_p[0]);
    const float dv0 = softplus_f(drag_v_p[0]);
    const float dv1 = softplus_f(drag_v_p[1]);
    const float dv2 = softplus_f(drag_v_p[2]);
    const float dc0 = softplus_f(drag_c_p[0]);
    const float dc1 = softplus_f(drag_c_p[1]);
    const float dc2 = softplus_f(drag_c_p[2]);
    const float dx = com_offset[0];
    const float dy = com_offset[1];

    const float A00 = gain * M00_F + grip;
    const float A11 = gain * M11_F + grip;
    const float A12 = gain * M12_F;
    const float A22 = gain * M22_F + grip;

    const float inv_mass    = 1.0f / MASS_F;
    const float inv_inertia = 1.0f / inertia;

    // --- load initial state ---
    const float* st = init_state + (size_t)b * 6;
    float x  = st[0];
    float y  = st[1];
    float th = st[2];
    float vx = st[3];
    float vy = st[4];
    float om = st[5];

    const float* __restrict__ cmd = cmd_all + (size_t)b * T * 3;
    float* __restrict__ o = out + (size_t)b * (size_t)(T + 1) * 6;

    // row 0 = initial state
    o[0] = x; o[1] = y; o[2] = th; o[3] = vx; o[4] = vy; o[5] = om;

    #pragma unroll 8
    for (int t = 0; t < T; ++t) {
        const float u0 = cmd[3 * t + 0];
        const float u1 = cmd[3 * t + 1];
        const float u2 = cmd[3 * t + 2];

        float c, s;
        sincosf(th, &s, &c);

        const float vxb = vx * c + vy * s;
        const float vyb = vy * c - vx * s;

        const float ex = u0 - vxb;
        const float ey = u1 - vyb;
        const float ez = u2 - om;

        float Fx = A00 * ex               - dv0 * vxb - dc0 * sgn_f(vxb);
        float Fy = A11 * ey + A12 * ez    - dv1 * vyb - dc1 * sgn_f(vyb);
        float Tz = A12 * ey + A22 * ez    - dv2 * om  - dc2 * sgn_f(om);

        const float Tc = Tz - (dx * Fy - dy * Fx);

        const float accx = Fx * inv_mass;
        const float accy = Fy * inv_mass;
        const float al   = Tc * inv_inertia;
        const float om2  = om * om;

        const float axb = accx - al * dy - om2 * dx;
        const float ayb = accy + al * dx - om2 * dy;

        const float axw = axb * c - ayb * s;
        const float ayw = axb * s + ayb * c;

        vx = vx + axw * DT_F;
        vy = vy + ayw * DT_F;
        om = om + al * DT_F;
        x  = x + vx * DT_F;
        y  = y + vy * DT_F;
        th = th + om * DT_F;
        // wrap to (-pi, pi] — matches atan2(sin,cos) for |th| < 3*pi
        th = (th >  PI_F) ? th - TWO_PI_F : th;
        th = (th < -PI_F) ? th + TWO_PI_F : th;

        float* ot = o + (size_t)(t + 1) * 6;
        ot[0] = x; ot[1] = y; ot[2] = th;
        ot[3] = vx; ot[4] = vy; ot[5] = om;
    }
}

extern "C" void kernel_launch(void* const* d_in, const int* in_sizes, int n_in,
                              void* d_out, int out_size, void* d_ws, size_t ws_size,
                              hipStream_t stream) {
    const float* init_state = (const float*)d_in[0];
    const float* cmd        = (const float*)d_in[1];
    const float* com_offset = (const float*)d_in[2];
    const float* inertia_p  = (const float*)d_in[3];
    const float* gain_p     = (const float*)d_in[4];
    const float* grip_p     = (const float*)d_in[5];
    const float* drag_v_p   = (const float*)d_in[6];
    const float* drag_c_p   = (const float*)d_in[7];
    float* out = (float*)d_out;

    const int B = in_sizes[0] / 6;
    const int T = in_sizes[1] / (3 * B);

    const int block = 64;
    const int grid = (B + block - 1) / block;
    hipLaunchKernelGGL(omni_robot_kernel, dim3(grid), dim3(block), 0, stream,
                       init_state, cmd, com_offset, inertia_p, gain_p, grip_p,
                       drag_v_p, drag_c_p, out, B, T);
}

// Round 2
// 533.842 us; speedup vs baseline: 1.0171x; 1.0171x over previous
//
#include <hip/hip_runtime.h>
#include <math.h>

// OmniRobotPhysics: B=8192 independent trajectories, T=1024 sequential steps.
// One thread per trajectory (128 wave64 total -> ~1 wave/CU, latency-bound).
// R1 -> R2 changes:
//  - chunked register double-buffer prefetch of cmd (16 steps = 12 float4/lane)
//  - inline branchless sincos (theta wrapped to (-pi,pi] each step, so a
//    Cody-Waite k*pi/2 reduction + minimax polys gives ~1ulp at ~18 flops)
//  - float2 stores (8B aligned: base b*24600, stride 24)

#define MASS_F 2.8f
#define DT_F 0.016f

// F F^T entries (double-precision from angles {60,130,230,300} deg, R=0.09):
#define M00_F 2.6736481776669306f
#define M11_F 1.3263518223330697f
#define M12_F (-0.025701769743577074f)
#define M22_F 0.0324f

#define PI_F 3.14159265358979323846f
#define TWO_PI_F 6.28318530717958647692f

__device__ __forceinline__ float softplus_f(float x) {
    float ax = fabsf(x);
    return fmaxf(x, 0.0f) + log1pf(expf(-ax));
}

__device__ __forceinline__ float sgn_f(float v) {
    return (v > 0.0f ? 1.0f : 0.0f) - (v < 0.0f ? 1.0f : 0.0f);
}

// sin/cos for |th| <~ 2*pi (theta is wrapped every step; |theta0| <~ 5.5).
// Cody-Waite reduction by k*pi/2, then degree-9/8 minimax on [-pi/4,pi/4].
__device__ __forceinline__ void fast_sincos(float th, float* sp, float* cp) {
    const float INV_PIO2 = 0.63661977236758134f;
    const float PIO2_HI  = 1.57079637050628662109375f;   // fp32(pi/2)
    const float PIO2_LO  = -4.37113900018624283e-8f;     // pi/2 - PIO2_HI
    float kf = rintf(th * INV_PIO2);
    int   k  = (int)kf;
    float r  = fmaf(-kf, PIO2_HI, th);
    r        = fmaf(-kf, PIO2_LO, r);
    float r2 = r * r;
    // sin(r)
    float ps = fmaf(r2, 2.7183114e-6f, -1.9515296e-4f);
    ps = fmaf(r2, ps, 8.3333310e-3f);
    ps = fmaf(r2, ps, -1.6666667e-1f);
    float sr = fmaf(r * r2, ps, r);
    // cos(r)
    float pc = fmaf(r2, 2.4760495e-5f, -1.3888889e-3f);
    pc = fmaf(r2, pc, 4.1666668e-2f);
    pc = fmaf(r2, pc, -0.5f);
    float cr = fmaf(r2, pc, 1.0f);
    int n = k & 3;
    float s = (n == 0) ? sr : (n == 1) ? cr : (n == 2) ? -sr : -cr;
    float c = (n == 0) ? cr : (n == 1) ? -sr : (n == 2) ? -cr : sr;
    *sp = s;
    *cp = c;
}

#define CHUNK 16   // steps per chunk; 16*3 floats = 12 float4 per lane

__global__ __launch_bounds__(64, 1)
void omni_robot_kernel(const float* __restrict__ init_state,   // (B, 6)
                       const float* __restrict__ cmd_all,      // (B, T, 3)
                       const float* __restrict__ com_offset,   // (2,)
                       const float* __restrict__ inertia_p,    // (1,)
                       const float* __restrict__ gain_p,       // (1,)
                       const float* __restrict__ grip_p,       // (1,)
                       const float* __restrict__ drag_v_p,     // (3,)
                       const float* __restrict__ drag_c_p,     // (3,)
                       float* __restrict__ out,                // (B, T+1, 6)
                       int B, int T)
{
    const int b = blockIdx.x * blockDim.x + threadIdx.x;
    if (b >= B) return;

    const float inertia = softplus_f(inertia_p[0]) + 1e-4f;
    const float gain    = softplus_f(gain_p[0]);
    const float grip    = softplus_f(grip_p[0]);
    const float dv0 = softplus_f(drag_v_p[0]);
    const float dv1 = softplus_f(drag_v_p[1]);
    const float dv2 = softplus_f(drag_v_p[2]);
    const float dc0 = softplus_f(drag_c_p[0]);
    const float dc1 = softplus_f(drag_c_p[1]);
    const float dc2 = softplus_f(drag_c_p[2]);
    const float dx = com_offset[0];
    const float dy = com_offset[1];

    const float A00 = gain * M00_F + grip;
    const float A11 = gain * M11_F + grip;
    const float A12 = gain * M12_F;
    const float A22 = gain * M22_F + grip;

    const float inv_mass    = 1.0f / MASS_F;
    const float inv_inertia = 1.0f / inertia;

    const float* st = init_state + (size_t)b * 6;
    float x  = st[0];
    float y  = st[1];
    float th = st[2];
    float vx = st[3];
    float vy = st[4];
    float om = st[5];

    const float* __restrict__ cmd = cmd_all + (size_t)b * T * 3;
    float* __restrict__ o = out + (size_t)b * (size_t)(T + 1) * 6;

    ((float2*)o)[0] = make_float2(x, y);
    ((float2*)o)[1] = make_float2(th, vx);
    ((float2*)o)[2] = make_float2(vy, om);

    // cmd base: b*T*3*4 = b*12288 bytes -> 16B aligned. 12 float4 per chunk.
    const float4* __restrict__ cmd4 = reinterpret_cast<const float4*>(cmd);
    const int nch = T / CHUNK;

    float4 cur[12];
    #pragma unroll
    for (int i = 0; i < 12; ++i) cur[i] = cmd4[i];

    for (int ch = 0; ch < nch; ++ch) {
        // prefetch next chunk (issued before the dependent compute chain;
        // waited on only at the next chunk's unpack)
        float4 nxt[12];
        #pragma unroll
        for (int i = 0; i < 12; ++i) nxt[i] = cur[i];
        if (ch + 1 < nch) {
            const float4* __restrict__ src = cmd4 + (size_t)(ch + 1) * 12;
            #pragma unroll
            for (int i = 0; i < 12; ++i) nxt[i] = src[i];
        }

        float u[3 * CHUNK];
        #pragma unroll
        for (int i = 0; i < 12; ++i) {
            u[4 * i + 0] = cur[i].x;
            u[4 * i + 1] = cur[i].y;
            u[4 * i + 2] = cur[i].z;
            u[4 * i + 3] = cur[i].w;
        }

        #pragma unroll
        for (int j = 0; j < CHUNK; ++j) {
            const int t = ch * CHUNK + j;
            const float u0 = u[3 * j + 0];
            const float u1 = u[3 * j + 1];
            const float u2 = u[3 * j + 2];

            float c, s;
            fast_sincos(th, &s, &c);

            const float vxb = vx * c + vy * s;
            const float vyb = vy * c - vx * s;

            const float ex = u0 - vxb;
            const float ey = u1 - vyb;
            const float ez = u2 - om;

            const float Fx = A00 * ex            - dv0 * vxb - dc0 * sgn_f(vxb);
            const float Fy = A11 * ey + A12 * ez - dv1 * vyb - dc1 * sgn_f(vyb);
            const float Tz = A12 * ey + A22 * ez - dv2 * om  - dc2 * sgn_f(om);

            const float Tc = Tz - (dx * Fy - dy * Fx);

            const float accx = Fx * inv_mass;
            const float accy = Fy * inv_mass;
            const float al   = Tc * inv_inertia;
            const float om2  = om * om;

            const float axb = accx - al * dy - om2 * dx;
            const float ayb = accy + al * dx - om2 * dy;

            const float axw = axb * c - ayb * s;
            const float ayw = axb * s + ayb * c;

            vx = vx + axw * DT_F;
            vy = vy + ayw * DT_F;
            om = om + al * DT_F;
            x  = x + vx * DT_F;
            y  = y + vy * DT_F;
            th = th + om * DT_F;
            th = (th >  PI_F) ? th - TWO_PI_F : th;
            th = (th < -PI_F) ? th + TWO_PI_F : th;

            float* ot = o + (size_t)(t + 1) * 6;
            ((float2*)ot)[0] = make_float2(x, y);
            ((float2*)ot)[1] = make_float2(th, vx);
            ((float2*)ot)[2] = make_float2(vy, om);
        }

        #pragma unroll
        for (int i = 0; i < 12; ++i) cur[i] = nxt[i];
    }

    // generic tail (T % CHUNK != 0); dead for T=1024
    for (int t = nch * CHUNK; t < T; ++t) {
        const float u0 = cmd[3 * t + 0];
        const float u1 = cmd[3 * t + 1];
        const float u2 = cmd[3 * t + 2];
        float c, s;
        fast_sincos(th, &s, &c);
        const float vxb = vx * c + vy * s;
        const float vyb = vy * c - vx * s;
        const float ex = u0 - vxb;
        const float ey = u1 - vyb;
        const float ez = u2 - om;
        const float Fx = A00 * ex            - dv0 * vxb - dc0 * sgn_f(vxb);
        const float Fy = A11 * ey + A12 * ez - dv1 * vyb - dc1 * sgn_f(vyb);
        const float Tz = A12 * ey + A22 * ez - dv2 * om  - dc2 * sgn_f(om);
        const float Tc = Tz - (dx * Fy - dy * Fx);
        const float accx = Fx * inv_mass;
        const float accy = Fy * inv_mass;
        const float al   = Tc * inv_inertia;
        const float om2  = om * om;
        const float axb = accx - al * dy - om2 * dx;
        const float ayb = accy + al * dx - om2 * dy;
        const float axw = axb * c - ayb * s;
        const float ayw = axb * s + ayb * c;
        vx = vx + axw * DT_F;
        vy = vy + ayw * DT_F;
        om = om + al * DT_F;
        x  = x + vx * DT_F;
        y  = y + vy * DT_F;
        th = th + om * DT_F;
        th = (th >  PI_F) ? th - TWO_PI_F : th;
        th = (th < -PI_F) ? th + TWO_PI_F : th;
        float* ot = o + (size_t)(t + 1) * 6;
        ((float2*)ot)[0] = make_float2(x, y);
        ((float2*)ot)[1] = make_float2(th, vx);
        ((float2*)ot)[2] = make_float2(vy, om);
    }
}

extern "C" void kernel_launch(void* const* d_in, const int* in_sizes, int n_in,
                              void* d_out, int out_size, void* d_ws, size_t ws_size,
                              hipStream_t stream) {
    const float* init_state = (const float*)d_in[0];
    const float* cmd        = (const float*)d_in[1];
    const float* com_offset = (const float*)d_in[2];
    const float* inertia_p  = (const float*)d_in[3];
    const float* gain_p     = (const float*)d_in[4];
    const float* grip_p     = (const float*)d_in[5];
    const float* drag_v_p   = (const float*)d_in[6];
    const float* drag_c_p   = (const float*)d_in[7];
    float* out = (float*)d_out;

    const int B = in_sizes[0] / 6;
    const int T = in_sizes[1] / (3 * B);

    const int block = 64;
    const int grid = (B + block - 1) / block;
    hipLaunchKernelGGL(omni_robot_kernel, dim3(grid), dim3(block), 0, stream,
                       init_state, cmd, com_offset, inertia_p, gain_p, grip_p,
                       drag_v_p, drag_c_p, out, B, T);
}